// Round 1
// baseline (2926.662 us; speedup 1.0000x reference)
//
#include <hip/hip_runtime.h>

// Net_66829691126193: 2-layer GCN + global_add_pool + 2-layer MLP head.
// N=100000 nodes, E=1600000 edges, F=H=64, G=128 graphs.

#define NODES_PER_GEMM_BLOCK 16

__global__ void k_fill1(float* __restrict__ deg, int n) {
    int i = blockIdx.x * blockDim.x + threadIdx.x;
    if (i < n) deg[i] = 1.0f;  // self-loop
}

__global__ void k_degcount(const int* __restrict__ dst, float* __restrict__ deg, int E) {
    int e = blockIdx.x * blockDim.x + threadIdx.x;
    if (e < E) unsafeAtomicAdd(&deg[dst[e]], 1.0f);
}

__global__ void k_rsqrt(float* __restrict__ d, int n) {
    int i = blockIdx.x * blockDim.x + threadIdx.x;
    if (i < n) d[i] = rsqrtf(d[i]);  // deg >= 1 always (self-loops)
}

// out[n,64] = (RELU? max(in,0) : in) @ W[64,64]
template <bool RELU>
__global__ void k_gemm64(const float* __restrict__ in, const float* __restrict__ W,
                         float* __restrict__ out, int n) {
    __shared__ float Ws[64 * 64];
    int t = threadIdx.x;
#pragma unroll
    for (int j = 0; j < 4; ++j) {
        int idx = (t + j * 256) * 4;
        *(float4*)&Ws[idx] = *(const float4*)&W[idx];
    }
    __syncthreads();

    int row = blockIdx.x * NODES_PER_GEMM_BLOCK + (t >> 4);
    int c = (t & 15) * 4;  // output column chunk
    if (row >= n) return;
    const float* inr = in + (size_t)row * 64;
    float4 acc = make_float4(0.f, 0.f, 0.f, 0.f);
#pragma unroll
    for (int k0 = 0; k0 < 64; k0 += 4) {
        float4 xv = *(const float4*)(inr + k0);  // 16 lanes same addr -> merged fetch
        if (RELU) {
            xv.x = fmaxf(xv.x, 0.f); xv.y = fmaxf(xv.y, 0.f);
            xv.z = fmaxf(xv.z, 0.f); xv.w = fmaxf(xv.w, 0.f);
        }
        float xs[4] = {xv.x, xv.y, xv.z, xv.w};
#pragma unroll
        for (int j = 0; j < 4; ++j) {
            float4 w = *(const float4*)&Ws[(k0 + j) * 64 + c];
            acc.x += xs[j] * w.x; acc.y += xs[j] * w.y;
            acc.z += xs[j] * w.z; acc.w += xs[j] * w.w;
        }
    }
    *(float4*)&out[(size_t)row * 64 + c] = acc;
}

// out[i,:] = xw[i,:] * dinv[i]^2 + b[:]   (self-loop contribution + bias)
__global__ void k_self(const float* __restrict__ xw, const float* __restrict__ dinv,
                       const float* __restrict__ b, float* __restrict__ out, int n) {
    int idx = blockIdx.x * blockDim.x + threadIdx.x;  // one float4 chunk each
    int node = idx >> 4;
    int c = (idx & 15) * 4;
    if (node >= n) return;
    float di = dinv[node];
    float s = di * di;
    float4 v = *(const float4*)&xw[(size_t)node * 64 + c];
    float4 bb = *(const float4*)&b[c];
    v.x = v.x * s + bb.x; v.y = v.y * s + bb.y;
    v.z = v.z * s + bb.z; v.w = v.w * s + bb.w;
    *(float4*)&out[(size_t)node * 64 + c] = v;
}

// out[dst,:] += xw[src,:] * dinv[src]*dinv[dst]; 16 lanes per edge, float4 each
__global__ void k_edge(const int* __restrict__ src, const int* __restrict__ dst,
                       const float* __restrict__ dinv, const float* __restrict__ xw,
                       float* __restrict__ out, int E) {
    int t = threadIdx.x;
    int e = blockIdx.x * 16 + (t >> 4);
    if (e >= E) return;
    int s = src[e];
    int d = dst[e];
    float nrm = dinv[s] * dinv[d];
    int c = (t & 15) * 4;
    float4 v = *(const float4*)&xw[(size_t)s * 64 + c];
    float* o = out + (size_t)d * 64 + c;
    unsafeAtomicAdd(o + 0, v.x * nrm);
    unsafeAtomicAdd(o + 1, v.y * nrm);
    unsafeAtomicAdd(o + 2, v.z * nrm);
    unsafeAtomicAdd(o + 3, v.w * nrm);
}

// One block per graph: pool relu(h) over sorted batch, then fc1+relu, fc2.
__global__ void k_pool_head(const float* __restrict__ h,  // pre-relu [n,64]
                            const int* __restrict__ batch,
                            const float* __restrict__ fc1w, const float* __restrict__ fc1b,
                            const float* __restrict__ fc2w, const float* __restrict__ fc2b,
                            float* __restrict__ out, int n) {
    int b = blockIdx.x;
    int t = threadIdx.x;
    // lower_bound(batch, b) and lower_bound(batch, b+1)
    int l = 0, r = n;
    while (l < r) { int m = (l + r) >> 1; if (batch[m] < b) l = m + 1; else r = m; }
    int lo = l;
    r = n;
    while (l < r) { int m = (l + r) >> 1; if (batch[m] < b + 1) l = m + 1; else r = m; }
    int hi = l;

    int f = t & 63, rr = t >> 6;
    float partial = 0.f;
    for (int i = lo + rr; i < hi; i += 4)
        partial += fmaxf(h[(size_t)i * 64 + f], 0.f);

    __shared__ float sm[4][64];
    __shared__ float gl[64];
    sm[rr][f] = partial;
    __syncthreads();
    if (t < 64) gl[t] = sm[0][t] + sm[1][t] + sm[2][t] + sm[3][t];
    __syncthreads();
    if (t < 64) {
        float acc = fc1b[t];
#pragma unroll 8
        for (int k = 0; k < 64; ++k) acc += gl[k] * fc1w[k * 64 + t];
        float v = fmaxf(acc, 0.f) * fc2w[t];
#pragma unroll
        for (int o = 32; o > 0; o >>= 1) v += __shfl_down(v, o, 64);
        if (t == 0) out[b] = v + fc2b[0];
    }
}

extern "C" void kernel_launch(void* const* d_in, const int* in_sizes, int n_in,
                              void* d_out, int out_size, void* d_ws, size_t ws_size,
                              hipStream_t stream) {
    const float* x    = (const float*)d_in[0];
    const int*   ei   = (const int*)d_in[1];
    const int*   batch= (const int*)d_in[2];
    const float* W1   = (const float*)d_in[3];
    const float* b1   = (const float*)d_in[4];
    const float* W2   = (const float*)d_in[5];
    const float* b2   = (const float*)d_in[6];
    const float* fc1w = (const float*)d_in[7];
    const float* fc1b = (const float*)d_in[8];
    const float* fc2w = (const float*)d_in[9];
    const float* fc2b = (const float*)d_in[10];
    float* out = (float*)d_out;

    int N = in_sizes[0] / 64;   // 100000
    int E = in_sizes[1] / 2;    // 1600000
    const int* src = ei;        // edge_index[0]
    const int* dstp = ei + E;   // edge_index[1]
    int G = out_size;           // 128 graphs

    float* A    = (float*)d_ws;            // [N,64]
    float* B    = A + (size_t)N * 64;      // [N,64]
    float* dinv = B + (size_t)N * 64;      // [N]

    dim3 blk(256);
    int nb_nodes = (N + 255) / 256;
    int nb_edges = (E + 255) / 256;
    int nb_gemm  = (N + NODES_PER_GEMM_BLOCK - 1) / NODES_PER_GEMM_BLOCK;
    int nb_nf4   = ((N * 16) + 255) / 256;
    int nb_edge16 = (E + 15) / 16;

    // degree -> dinv (in place)
    k_fill1<<<nb_nodes, blk, 0, stream>>>(dinv, N);
    k_degcount<<<nb_edges, blk, 0, stream>>>(dstp, dinv, E);
    k_rsqrt<<<nb_nodes, blk, 0, stream>>>(dinv, N);

    // layer 1: A = x @ W1 ; B = A*dinv^2 + b1 ; B += scatter(A)
    k_gemm64<false><<<nb_gemm, blk, 0, stream>>>(x, W1, A, N);
    k_self<<<nb_nf4, blk, 0, stream>>>(A, dinv, b1, B, N);
    k_edge<<<nb_edge16, blk, 0, stream>>>(src, dstp, dinv, A, B, E);

    // layer 2: A = relu(B) @ W2 ; B = A*dinv^2 + b2 ; B += scatter(A)
    k_gemm64<true><<<nb_gemm, blk, 0, stream>>>(B, W2, A, N);
    k_self<<<nb_nf4, blk, 0, stream>>>(A, dinv, b2, B, N);
    k_edge<<<nb_edge16, blk, 0, stream>>>(src, dstp, dinv, A, B, E);

    // pool (relu fused) + MLP head
    k_pool_head<<<G, blk, 0, stream>>>(B, batch, fc1w, fc1b, fc2w, fc2b, out, N);
}

// Round 2
// 1204.937 us; speedup vs baseline: 2.4289x; 2.4289x over previous
//
#include <hip/hip_runtime.h>

// Net_66829691126193: 2-layer GCN + global_add_pool + 2-layer MLP head.
// N=100000 nodes, E=1600000 edges, F=H=64, G=128 graphs.
// Strategy: build by-dst CSR per call, aggregate by GATHER (no float atomics).

#define NODES_PER_GEMM_BLOCK 16
#define SCAN_CHUNK 1024

__global__ void k_zero_int(int* __restrict__ p, int n) {
    int i = blockIdx.x * blockDim.x + threadIdx.x;
    if (i < n) p[i] = 0;
}

__global__ void k_hist(const int* __restrict__ dst, int* __restrict__ cnt, int E) {
    int e = blockIdx.x * blockDim.x + threadIdx.x;
    if (e < E) atomicAdd(&cnt[dst[e]], 1);
}

// partials[b] = sum of cnt over block b's 1024-elem chunk
__global__ void k_partial_sum(const int* __restrict__ cnt, int* __restrict__ partials, int n) {
    __shared__ int sm[256];
    int base = blockIdx.x * SCAN_CHUNK;
    int t = threadIdx.x;
    int s = 0;
#pragma unroll
    for (int j = 0; j < 4; ++j) {
        int i = base + t + j * 256;
        if (i < n) s += cnt[i];
    }
    sm[t] = s;
    __syncthreads();
    for (int o = 128; o > 0; o >>= 1) {
        if (t < o) sm[t] += sm[t + o];
        __syncthreads();
    }
    if (t == 0) partials[blockIdx.x] = sm[0];
}

__global__ void k_scan_partials(int* __restrict__ partials, int nb) {
    if (threadIdx.x == 0 && blockIdx.x == 0) {
        int acc = 0;
        for (int i = 0; i < nb; ++i) { int v = partials[i]; partials[i] = acc; acc += v; }
    }
}

// exclusive scan within chunk + partial offset -> row_ptr; also dinv = rsqrt(deg+1)
__global__ void k_scan_final(const int* __restrict__ cnt, const int* __restrict__ partials,
                             int* __restrict__ row_ptr, float* __restrict__ dinv,
                             int n, int E) {
    __shared__ int sm[256];
    int base = blockIdx.x * SCAN_CHUNK;
    int t = threadIdx.x;
    int v[4];
    int loc = 0;
#pragma unroll
    for (int j = 0; j < 4; ++j) {
        int i = base + t * 4 + j;
        v[j] = (i < n) ? cnt[i] : 0;
        loc += v[j];
    }
    sm[t] = loc;
    __syncthreads();
    for (int o = 1; o < 256; o <<= 1) {
        int x = (t >= o) ? sm[t - o] : 0;
        __syncthreads();
        sm[t] += x;
        __syncthreads();
    }
    int off = partials[blockIdx.x] + sm[t] - loc;  // exclusive prefix for elem t*4
#pragma unroll
    for (int j = 0; j < 4; ++j) {
        int i = base + t * 4 + j;
        if (i < n) {
            row_ptr[i] = off;
            off += v[j];
            dinv[i] = rsqrtf((float)(v[j] + 1));  // +1 self-loop
        }
    }
    if (blockIdx.x == 0 && t == 0) row_ptr[n] = E;
}

__global__ void k_scatter(const int* __restrict__ src, const int* __restrict__ dst,
                          const int* __restrict__ row_ptr, int* __restrict__ cursor,
                          int* __restrict__ col, int E) {
    int e = blockIdx.x * blockDim.x + threadIdx.x;
    if (e < E) {
        int d = dst[e];
        int pos = row_ptr[d] + atomicAdd(&cursor[d], 1);
        col[pos] = src[e];
    }
}

// out[n,64] = (RELU? max(in,0) : in) @ W[64,64], row-scaled by dinv[row]
template <bool RELU>
__global__ void k_gemm64(const float* __restrict__ in, const float* __restrict__ W,
                         const float* __restrict__ dinv, float* __restrict__ out, int n) {
    __shared__ float Ws[64 * 64];
    int t = threadIdx.x;
#pragma unroll
    for (int j = 0; j < 4; ++j) {
        int idx = (t + j * 256) * 4;
        *(float4*)&Ws[idx] = *(const float4*)&W[idx];
    }
    __syncthreads();

    int row = blockIdx.x * NODES_PER_GEMM_BLOCK + (t >> 4);
    int c = (t & 15) * 4;
    if (row >= n) return;
    const float* inr = in + (size_t)row * 64;
    float4 acc = make_float4(0.f, 0.f, 0.f, 0.f);
#pragma unroll
    for (int k0 = 0; k0 < 64; k0 += 4) {
        float4 xv = *(const float4*)(inr + k0);
        if (RELU) {
            xv.x = fmaxf(xv.x, 0.f); xv.y = fmaxf(xv.y, 0.f);
            xv.z = fmaxf(xv.z, 0.f); xv.w = fmaxf(xv.w, 0.f);
        }
        float xs[4] = {xv.x, xv.y, xv.z, xv.w};
#pragma unroll
        for (int j = 0; j < 4; ++j) {
            float4 w = *(const float4*)&Ws[(k0 + j) * 64 + c];
            acc.x += xs[j] * w.x; acc.y += xs[j] * w.y;
            acc.z += xs[j] * w.z; acc.w += xs[j] * w.w;
        }
    }
    float s = dinv[row];
    acc.x *= s; acc.y *= s; acc.z *= s; acc.w *= s;
    *(float4*)&out[(size_t)row * 64 + c] = acc;
}

// out[d,:] = (y[d,:] + sum_{e in row d} y[col[e],:]) * dinv[d] + b
// y is already row-scaled by dinv[src]. 16 lanes per node, float4 per lane.
__global__ void k_gather(const float* __restrict__ y, const int* __restrict__ row_ptr,
                         const int* __restrict__ col, const float* __restrict__ dinv,
                         const float* __restrict__ b, float* __restrict__ out, int n) {
    int t = threadIdx.x;
    int node = blockIdx.x * 16 + (t >> 4);
    if (node >= n) return;
    int c = (t & 15) * 4;
    int beg = row_ptr[node], end = row_ptr[node + 1];
    float4 acc = *(const float4*)&y[(size_t)node * 64 + c];  // self-loop term
    int j = beg;
    for (; j + 1 < end; j += 2) {  // 2-deep to overlap index->data latency
        int s0 = col[j], s1 = col[j + 1];
        float4 v0 = *(const float4*)&y[(size_t)s0 * 64 + c];
        float4 v1 = *(const float4*)&y[(size_t)s1 * 64 + c];
        acc.x += v0.x + v1.x; acc.y += v0.y + v1.y;
        acc.z += v0.z + v1.z; acc.w += v0.w + v1.w;
    }
    if (j < end) {
        int s0 = col[j];
        float4 v0 = *(const float4*)&y[(size_t)s0 * 64 + c];
        acc.x += v0.x; acc.y += v0.y; acc.z += v0.z; acc.w += v0.w;
    }
    float dn = dinv[node];
    float4 bb = *(const float4*)&b[c];
    acc.x = acc.x * dn + bb.x; acc.y = acc.y * dn + bb.y;
    acc.z = acc.z * dn + bb.z; acc.w = acc.w * dn + bb.w;
    *(float4*)&out[(size_t)node * 64 + c] = acc;
}

// One block per graph: pool relu(h) over sorted batch, then fc1+relu, fc2.
__global__ void k_pool_head(const float* __restrict__ h, const int* __restrict__ batch,
                            const float* __restrict__ fc1w, const float* __restrict__ fc1b,
                            const float* __restrict__ fc2w, const float* __restrict__ fc2b,
                            float* __restrict__ out, int n) {
    int b = blockIdx.x;
    int t = threadIdx.x;
    int l = 0, r = n;
    while (l < r) { int m = (l + r) >> 1; if (batch[m] < b) l = m + 1; else r = m; }
    int lo = l;
    r = n;
    while (l < r) { int m = (l + r) >> 1; if (batch[m] < b + 1) l = m + 1; else r = m; }
    int hi = l;

    int f = t & 63, rr = t >> 6;
    float partial = 0.f;
    for (int i = lo + rr; i < hi; i += 4)
        partial += fmaxf(h[(size_t)i * 64 + f], 0.f);

    __shared__ float sm[4][64];
    __shared__ float gl[64];
    sm[rr][f] = partial;
    __syncthreads();
    if (t < 64) gl[t] = sm[0][t] + sm[1][t] + sm[2][t] + sm[3][t];
    __syncthreads();
    if (t < 64) {
        float acc = fc1b[t];
#pragma unroll 8
        for (int k = 0; k < 64; ++k) acc += gl[k] * fc1w[k * 64 + t];
        float v = fmaxf(acc, 0.f) * fc2w[t];
#pragma unroll
        for (int o = 32; o > 0; o >>= 1) v += __shfl_down(v, o, 64);
        if (t == 0) out[b] = v + fc2b[0];
    }
}

extern "C" void kernel_launch(void* const* d_in, const int* in_sizes, int n_in,
                              void* d_out, int out_size, void* d_ws, size_t ws_size,
                              hipStream_t stream) {
    const float* x    = (const float*)d_in[0];
    const int*   ei   = (const int*)d_in[1];
    const int*   batch= (const int*)d_in[2];
    const float* W1   = (const float*)d_in[3];
    const float* b1   = (const float*)d_in[4];
    const float* W2   = (const float*)d_in[5];
    const float* b2   = (const float*)d_in[6];
    const float* fc1w = (const float*)d_in[7];
    const float* fc1b = (const float*)d_in[8];
    const float* fc2w = (const float*)d_in[9];
    const float* fc2b = (const float*)d_in[10];
    float* out = (float*)d_out;

    int N = in_sizes[0] / 64;   // 100000
    int E = in_sizes[1] / 2;    // 1600000
    const int* src = ei;
    const int* dstp = ei + E;
    int G = out_size;           // 128

    // workspace layout
    float* A    = (float*)d_ws;               // [N,64]  y buffer
    float* B    = A + (size_t)N * 64;         // [N,64]  conv output
    float* dinv = B + (size_t)N * 64;         // [N]
    int*   row_ptr = (int*)(dinv + N);        // [N+1]
    int*   cursor  = row_ptr + (N + 1);       // [N] (also degree counts)
    int*   col     = cursor + N;              // [E]
    int*   partials= col + E;                 // [<=128]

    dim3 blk(256);
    int nb_nodes = (N + 255) / 256;
    int nb_edges = (E + 255) / 256;
    int nb_gemm  = (N + NODES_PER_GEMM_BLOCK - 1) / NODES_PER_GEMM_BLOCK;
    int nb_scan  = (N + SCAN_CHUNK - 1) / SCAN_CHUNK;
    int nb_g16   = (N + 15) / 16;

    // CSR build
    k_zero_int<<<nb_nodes, blk, 0, stream>>>(cursor, N);
    k_hist<<<nb_edges, blk, 0, stream>>>(dstp, cursor, E);
    k_partial_sum<<<nb_scan, blk, 0, stream>>>(cursor, partials, N);
    k_scan_partials<<<1, 64, 0, stream>>>(partials, nb_scan);
    k_scan_final<<<nb_scan, blk, 0, stream>>>(cursor, partials, row_ptr, dinv, N, E);
    k_zero_int<<<nb_nodes, blk, 0, stream>>>(cursor, N);
    k_scatter<<<nb_edges, blk, 0, stream>>>(src, dstp, row_ptr, cursor, col, E);

    // layer 1: A = (x @ W1)*dinv ; B = gather(A) + b1
    k_gemm64<false><<<nb_gemm, blk, 0, stream>>>(x, W1, dinv, A, N);
    k_gather<<<nb_g16, blk, 0, stream>>>(A, row_ptr, col, dinv, b1, B, N);

    // layer 2: A = (relu(B) @ W2)*dinv ; B = gather(A) + b2
    k_gemm64<true><<<nb_gemm, blk, 0, stream>>>(B, W2, dinv, A, N);
    k_gather<<<nb_g16, blk, 0, stream>>>(A, row_ptr, col, dinv, b2, B, N);

    // pool (relu fused) + MLP head
    k_pool_head<<<G, blk, 0, stream>>>(B, batch, fc1w, fc1b, fc2w, fc2b, out, N);
}

// Round 4
// 267.662 us; speedup vs baseline: 10.9342x; 4.5017x over previous
//
#include <hip/hip_runtime.h>

// Net_66829691126193: 2-layer GCN + global_add_pool + 2-layer MLP head.
// N=100000 nodes, E=1600000 edges, F=H=64, G=128 graphs.
// CSR by bucketed counting sort (cache-friendly), gather aggregation,
// fused gather+gemm and gather+pool.

#define NODES_PER_GEMM_BLOCK 16
#define BSHIFT 9
#define NBK_MAX 256
#define EPT 16

__global__ void k_zero_int(int* __restrict__ p, int n) {
    int i = blockIdx.x * blockDim.x + threadIdx.x;
    if (i < n) p[i] = 0;
}

// bucket histogram: bcnt[dst>>BSHIFT]++
__global__ void k_bhist(const int* __restrict__ dst, int* __restrict__ bcnt,
                        int E, int nbk) {
    __shared__ int c[NBK_MAX];
    int t = threadIdx.x;
    for (int i = t; i < nbk; i += 256) c[i] = 0;
    __syncthreads();
    for (int e = blockIdx.x * blockDim.x + t; e < E; e += gridDim.x * blockDim.x)
        atomicAdd(&c[dst[e] >> BSHIFT], 1);
    __syncthreads();
    for (int i = t; i < nbk; i += 256)
        if (c[i]) atomicAdd(&bcnt[i], c[i]);
}

// single block: exclusive-scan bcnt -> bbase, bcursor; row_ptr[n]=E
__global__ void k_bscan(const int* __restrict__ bcnt, int* __restrict__ bbase,
                        int* __restrict__ bcursor, int* __restrict__ row_ptr,
                        int nbk, int n, int E) {
    __shared__ int s[NBK_MAX];
    int t = threadIdx.x;
    int v0 = (t < nbk) ? bcnt[t] : 0;
    s[t] = v0;
    __syncthreads();
    for (int o = 1; o < 256; o <<= 1) {
        int v = (t >= o) ? s[t - o] : 0;
        __syncthreads();
        s[t] += v;
        __syncthreads();
    }
    int exc = s[t] - v0;
    if (t < nbk) { bbase[t] = exc; bcursor[t] = exc; }
    if (t == 0) { bbase[nbk] = E; row_ptr[n] = E; }
}

// bin (dst,src) pairs into bucket segments of ebuf
__global__ void k_binpairs(const int* __restrict__ src, const int* __restrict__ dst,
                           int* __restrict__ bcursor, int2* __restrict__ ebuf,
                           int E, int nbk) {
    __shared__ int cnt[NBK_MAX], base[NBK_MAX];
    int t = threadIdx.x;
    for (int i = t; i < nbk; i += 256) cnt[i] = 0;
    __syncthreads();
    int e0 = blockIdx.x * (256 * EPT);
    int d[EPT], s[EPT];
#pragma unroll
    for (int j = 0; j < EPT; ++j) {
        int e = e0 + j * 256 + t;
        if (e < E) {
            d[j] = dst[e]; s[j] = src[e];
            atomicAdd(&cnt[d[j] >> BSHIFT], 1);
        } else d[j] = -1;
    }
    __syncthreads();
    for (int i = t; i < nbk; i += 256)
        base[i] = cnt[i] ? atomicAdd(&bcursor[i], cnt[i]) : 0;
    __syncthreads();
    for (int i = t; i < nbk; i += 256) cnt[i] = 0;
    __syncthreads();
#pragma unroll
    for (int j = 0; j < EPT; ++j) {
        if (d[j] >= 0) {
            int b = d[j] >> BSHIFT;
            int r = atomicAdd(&cnt[b], 1);
            ebuf[base[b] + r] = make_int2(d[j], s[j]);
        }
    }
}

// one block per bucket: local count+scan -> row_ptr, dinv, col
__global__ void k_bucket_csr(const int2* __restrict__ ebuf, const int* __restrict__ bbase,
                             int* __restrict__ row_ptr, int* __restrict__ col,
                             float* __restrict__ dinv, int n) {
    __shared__ int cnt[512], ofs[512], cur[512];
    __shared__ int ssum[256];
    int b = blockIdx.x;
    int t = threadIdx.x;
    int nodeBase = b << BSHIFT;
    int nNodes = min(512, n - nodeBase);
    int beg = bbase[b], end = bbase[b + 1];
    cnt[t] = 0; cnt[t + 256] = 0;
    __syncthreads();
    for (int e = beg + t; e < end; e += 256)
        atomicAdd(&cnt[ebuf[e].x - nodeBase], 1);
    __syncthreads();
    int a0 = cnt[2 * t], a1 = cnt[2 * t + 1];
    ssum[t] = a0 + a1;
    __syncthreads();
    for (int o = 1; o < 256; o <<= 1) {
        int v = (t >= o) ? ssum[t - o] : 0;
        __syncthreads();
        ssum[t] += v;
        __syncthreads();
    }
    int exc = ssum[t] - (a0 + a1);
    ofs[2 * t] = exc;       ofs[2 * t + 1] = exc + a0;
    cur[2 * t] = exc;       cur[2 * t + 1] = exc + a0;
    __syncthreads();
    for (int i = t; i < nNodes; i += 256) {
        row_ptr[nodeBase + i] = beg + ofs[i];
        dinv[nodeBase + i] = rsqrtf((float)(cnt[i] + 1));  // +1 self-loop
    }
    __syncthreads();
    for (int e = beg + t; e < end; e += 256) {
        int2 p = ebuf[e];
        int r = atomicAdd(&cur[p.x - nodeBase], 1);
        col[beg + r] = p.y;
    }
}

// out[n,64] = ((RELU? relu(in) : in) @ W) * dinv[row]
template <bool RELU>
__global__ void k_gemm64(const float* __restrict__ in, const float* __restrict__ W,
                         const float* __restrict__ dinv, float* __restrict__ out, int n) {
    __shared__ float Ws[64 * 64];
    int t = threadIdx.x;
#pragma unroll
    for (int j = 0; j < 4; ++j) {
        int idx = (t + j * 256) * 4;
        *(float4*)&Ws[idx] = *(const float4*)&W[idx];
    }
    __syncthreads();
    int row = blockIdx.x * NODES_PER_GEMM_BLOCK + (t >> 4);
    int c = (t & 15) * 4;
    if (row >= n) return;
    const float* inr = in + (size_t)row * 64;
    float4 acc = make_float4(0.f, 0.f, 0.f, 0.f);
#pragma unroll
    for (int k0 = 0; k0 < 64; k0 += 4) {
        float4 xv = *(const float4*)(inr + k0);
        if (RELU) {
            xv.x = fmaxf(xv.x, 0.f); xv.y = fmaxf(xv.y, 0.f);
            xv.z = fmaxf(xv.z, 0.f); xv.w = fmaxf(xv.w, 0.f);
        }
        float xs[4] = {xv.x, xv.y, xv.z, xv.w};
#pragma unroll
        for (int j = 0; j < 4; ++j) {
            float4 w = *(const float4*)&Ws[(k0 + j) * 64 + c];
            acc.x += xs[j] * w.x; acc.y += xs[j] * w.y;
            acc.z += xs[j] * w.z; acc.w += xs[j] * w.w;
        }
    }
    float s = dinv[row];
    acc.x *= s; acc.y *= s; acc.z *= s; acc.w *= s;
    *(float4*)&out[(size_t)row * 64 + c] = acc;
}

// Fused: h = relu((y[d] + sum y[col]) * dinv[d] + b1); y2[d] = (h @ W2)*dinv[d]
__global__ void k_gather_gemm(const float* __restrict__ y, const int* __restrict__ row_ptr,
                              const int* __restrict__ col, const float* __restrict__ dinv,
                              const float* __restrict__ bias, const float* __restrict__ W,
                              float* __restrict__ out, int n) {
    __shared__ float Ws[64 * 64];
    __shared__ float rowb[16][68];
    int t = threadIdx.x;
#pragma unroll
    for (int j = 0; j < 4; ++j) {
        int idx = (t + j * 256) * 4;
        *(float4*)&Ws[idx] = *(const float4*)&W[idx];
    }
    int node = blockIdx.x * 16 + (t >> 4);
    int c = (t & 15) * 4;
    int nl = t >> 4;
    bool active = node < n;
    float dn = 0.f;
    if (active) {
        int beg = row_ptr[node], end = row_ptr[node + 1];
        float4 acc = *(const float4*)&y[(size_t)node * 64 + c];
        int j = beg;
        for (; j + 1 < end; j += 2) {
            int s0 = col[j], s1 = col[j + 1];
            float4 v0 = *(const float4*)&y[(size_t)s0 * 64 + c];
            float4 v1 = *(const float4*)&y[(size_t)s1 * 64 + c];
            acc.x += v0.x + v1.x; acc.y += v0.y + v1.y;
            acc.z += v0.z + v1.z; acc.w += v0.w + v1.w;
        }
        if (j < end) {
            int s0 = col[j];
            float4 v0 = *(const float4*)&y[(size_t)s0 * 64 + c];
            acc.x += v0.x; acc.y += v0.y; acc.z += v0.z; acc.w += v0.w;
        }
        dn = dinv[node];
        float4 bb = *(const float4*)&bias[c];
        rowb[nl][c + 0] = fmaxf(acc.x * dn + bb.x, 0.f);
        rowb[nl][c + 1] = fmaxf(acc.y * dn + bb.y, 0.f);
        rowb[nl][c + 2] = fmaxf(acc.z * dn + bb.z, 0.f);
        rowb[nl][c + 3] = fmaxf(acc.w * dn + bb.w, 0.f);
    }
    __syncthreads();
    if (!active) return;
    float4 o = make_float4(0.f, 0.f, 0.f, 0.f);
#pragma unroll
    for (int k0 = 0; k0 < 64; k0 += 4) {
        float4 xv = *(const float4*)&rowb[nl][k0];
        float xs[4] = {xv.x, xv.y, xv.z, xv.w};
#pragma unroll
        for (int j = 0; j < 4; ++j) {
            float4 w = *(const float4*)&Ws[(k0 + j) * 64 + c];
            o.x += xs[j] * w.x; o.y += xs[j] * w.y;
            o.z += xs[j] * w.z; o.w += xs[j] * w.w;
        }
    }
    o.x *= dn; o.y *= dn; o.z *= dn; o.w *= dn;
    *(float4*)&out[(size_t)node * 64 + c] = o;
}

// Fused: h = relu((y[d] + sum y[col]) * dinv[d] + b2); g[batch[d]] += h
__global__ void k_gather_pool(const float* __restrict__ y, const int* __restrict__ row_ptr,
                              const int* __restrict__ col, const float* __restrict__ dinv,
                              const float* __restrict__ bias, const int* __restrict__ batch,
                              float* __restrict__ g, int n) {
    int t = threadIdx.x;
    int blk0 = (int)blockIdx.x * 16;
    int node = blk0 + (t >> 4);
    int c = (t & 15) * 4;
    __shared__ int bFirst, bLast;
    __shared__ float4 sm[4][16];
    if (t == 0) {
        int i0 = blk0 < n - 1 ? blk0 : n - 1;
        bFirst = batch[i0];
    }
    if (t == 255) {
        int i1 = blk0 + 15 < n - 1 ? blk0 + 15 : n - 1;
        bLast = batch[i1];
    }
    bool active = node < n;
    float4 h = make_float4(0.f, 0.f, 0.f, 0.f);
    int bt = 0;
    if (active) {
        int beg = row_ptr[node], end = row_ptr[node + 1];
        float4 acc = *(const float4*)&y[(size_t)node * 64 + c];
        int j = beg;
        for (; j + 1 < end; j += 2) {
            int s0 = col[j], s1 = col[j + 1];
            float4 v0 = *(const float4*)&y[(size_t)s0 * 64 + c];
            float4 v1 = *(const float4*)&y[(size_t)s1 * 64 + c];
            acc.x += v0.x + v1.x; acc.y += v0.y + v1.y;
            acc.z += v0.z + v1.z; acc.w += v0.w + v1.w;
        }
        if (j < end) {
            int s0 = col[j];
            float4 v0 = *(const float4*)&y[(size_t)s0 * 64 + c];
            acc.x += v0.x; acc.y += v0.y; acc.z += v0.z; acc.w += v0.w;
        }
        float dn = dinv[node];
        float4 bb = *(const float4*)&bias[c];
        h.x = fmaxf(acc.x * dn + bb.x, 0.f);
        h.y = fmaxf(acc.y * dn + bb.y, 0.f);
        h.z = fmaxf(acc.z * dn + bb.z, 0.f);
        h.w = fmaxf(acc.w * dn + bb.w, 0.f);
        bt = batch[node];
    }
    __syncthreads();
    if (bFirst == bLast) {
        // whole block same graph: reduce 4 nodes within wave, then 4 waves in LDS
        float4 v = h;
        v.x += __shfl_xor(v.x, 16, 64); v.y += __shfl_xor(v.y, 16, 64);
        v.z += __shfl_xor(v.z, 16, 64); v.w += __shfl_xor(v.w, 16, 64);
        v.x += __shfl_xor(v.x, 32, 64); v.y += __shfl_xor(v.y, 32, 64);
        v.z += __shfl_xor(v.z, 32, 64); v.w += __shfl_xor(v.w, 32, 64);
        if ((t & 63) < 16) sm[t >> 6][t & 15] = v;
        __syncthreads();
        if (t < 16) {
            float4 a = sm[0][t], b2 = sm[1][t], c2 = sm[2][t], d2 = sm[3][t];
            float4 tot;
            tot.x = a.x + b2.x + c2.x + d2.x; tot.y = a.y + b2.y + c2.y + d2.y;
            tot.z = a.z + b2.z + c2.z + d2.z; tot.w = a.w + b2.w + c2.w + d2.w;
            float* gp = &g[(size_t)bFirst * 64 + t * 4];
            unsafeAtomicAdd(gp + 0, tot.x); unsafeAtomicAdd(gp + 1, tot.y);
            unsafeAtomicAdd(gp + 2, tot.z); unsafeAtomicAdd(gp + 3, tot.w);
        }
    } else if (active) {
        float* gp = &g[(size_t)bt * 64 + c];
        unsafeAtomicAdd(gp + 0, h.x); unsafeAtomicAdd(gp + 1, h.y);
        unsafeAtomicAdd(gp + 2, h.z); unsafeAtomicAdd(gp + 3, h.w);
    }
}

// one block (64 thr) per graph: out = relu(g@fc1+b)@fc2+b
__global__ void k_head(const float* __restrict__ g, const float* __restrict__ fc1w,
                       const float* __restrict__ fc1b, const float* __restrict__ fc2w,
                       const float* __restrict__ fc2b, float* __restrict__ out) {
    int b = blockIdx.x, t = threadIdx.x;
    __shared__ float gl[64];
    gl[t] = g[(size_t)b * 64 + t];
    __syncthreads();
    float acc = fc1b[t];
#pragma unroll 8
    for (int k = 0; k < 64; ++k) acc += gl[k] * fc1w[k * 64 + t];
    float v = fmaxf(acc, 0.f) * fc2w[t];
#pragma unroll
    for (int o = 32; o > 0; o >>= 1) v += __shfl_down(v, o, 64);
    if (t == 0) out[b] = v + fc2b[0];
}

extern "C" void kernel_launch(void* const* d_in, const int* in_sizes, int n_in,
                              void* d_out, int out_size, void* d_ws, size_t ws_size,
                              hipStream_t stream) {
    const float* x    = (const float*)d_in[0];
    const int*   ei   = (const int*)d_in[1];
    const int*   batch= (const int*)d_in[2];
    const float* W1   = (const float*)d_in[3];
    const float* b1   = (const float*)d_in[4];
    const float* W2   = (const float*)d_in[5];
    const float* b2   = (const float*)d_in[6];
    const float* fc1w = (const float*)d_in[7];
    const float* fc1b = (const float*)d_in[8];
    const float* fc2w = (const float*)d_in[9];
    const float* fc2b = (const float*)d_in[10];
    float* out = (float*)d_out;

    int N = in_sizes[0] / 64;   // 100000
    int E = in_sizes[1] / 2;    // 1600000
    const int* src = ei;
    const int* dstp = ei + E;
    int G = out_size;           // 128
    int nbk = (N + (1 << BSHIFT) - 1) >> BSHIFT;  // 196

    // workspace layout (4-byte units)
    float* y1      = (float*)d_ws;                       // [N*64]
    float* scratch = y1 + (size_t)N * 64;                // max(ebuf 2E ints, y2 N*64)
    int2*  ebuf    = (int2*)scratch;                     // [E] pairs
    float* y2      = scratch;                            // [N*64] (after ebuf dead)
    float* dinv    = scratch + (size_t)N * 64;           // [N]
    int*   row_ptr = (int*)(dinv + N);                   // [N+1]
    int*   col     = row_ptr + (N + 1);                  // [E]
    int*   bbase   = col + E;                            // [NBK_MAX+1]
    int*   bcursor = bbase + (NBK_MAX + 1);              // [NBK_MAX]
    int*   bcnt    = bcursor + NBK_MAX;                  // [NBK_MAX]
    float* g       = (float*)(bcnt + NBK_MAX);           // [G*64] (needs zero)

    dim3 blk(256);
    int nzero = NBK_MAX + G * 64;          // bcnt + g contiguous
    int nb_pairs = (E + 256 * EPT - 1) / (256 * EPT);
    int nb_gemm  = (N + NODES_PER_GEMM_BLOCK - 1) / NODES_PER_GEMM_BLOCK;
    int nb_g16   = (N + 15) / 16;

    // CSR build (bucketed counting sort)
    k_zero_int<<<(nzero + 255) / 256, blk, 0, stream>>>(bcnt, nzero);
    k_bhist<<<1024, blk, 0, stream>>>(dstp, bcnt, E, nbk);
    k_bscan<<<1, blk, 0, stream>>>(bcnt, bbase, bcursor, row_ptr, nbk, N, E);
    k_binpairs<<<nb_pairs, blk, 0, stream>>>(src, dstp, bcursor, ebuf, E, nbk);
    k_bucket_csr<<<nbk, blk, 0, stream>>>(ebuf, bbase, row_ptr, col, dinv, N);

    // layer 1 gemm: y1 = (x @ W1)*dinv
    k_gemm64<false><<<nb_gemm, blk, 0, stream>>>(x, W1, dinv, y1, N);
    // fused layer1-aggregate + layer2 gemm: y2 = (relu(agg(y1)+b1) @ W2)*dinv
    k_gather_gemm<<<nb_g16, blk, 0, stream>>>(y1, row_ptr, col, dinv, b1, W2, y2, N);
    // fused layer2-aggregate + relu + pool: g += relu(agg(y2)+b2)
    k_gather_pool<<<nb_g16, blk, 0, stream>>>(y2, row_ptr, col, dinv, b2, batch, g, N);
    // MLP head
    k_head<<<G, 64, 0, stream>>>(g, fc1w, fc1b, fc2w, fc2b, out);
}

// Round 5
// 223.555 us; speedup vs baseline: 13.0915x; 1.1973x over previous
//
#include <hip/hip_runtime.h>
#include <hip/hip_fp16.h>

// Net_66829691126193: 2-layer GCN + global_add_pool + 2-layer MLP head.
// N=100000 nodes, E=1600000 edges, F=H=64, G=128 graphs.
// CSR by bucketed counting sort; gather aggregation with fp16 intermediate
// rows (fp32 compute) + 4-deep unroll for latency hiding.

#define NODES_PER_GEMM_BLOCK 16
#define BSHIFT 9
#define NBK_MAX 256
#define EPT 16

__device__ __forceinline__ void add4(float4& a, const float4& v) {
    a.x += v.x; a.y += v.y; a.z += v.z; a.w += v.w;
}

union HU2 { uint2 u; __half2 h[2]; };

__device__ __forceinline__ float4 ld_h4(const __half* __restrict__ y, int node, int c) {
    HU2 p;
    p.u = *(const uint2*)(y + ((size_t)node << 6) + c);
    float2 f0 = __half22float2(p.h[0]);
    float2 f1 = __half22float2(p.h[1]);
    return make_float4(f0.x, f0.y, f1.x, f1.y);
}

__device__ __forceinline__ void st_h4(__half* __restrict__ y, int node, int c, float4 v) {
    HU2 p;
    p.h[0] = __floats2half2_rn(v.x, v.y);
    p.h[1] = __floats2half2_rn(v.z, v.w);
    *(uint2*)(y + ((size_t)node << 6) + c) = p.u;
}

__global__ void k_zero_int(int* __restrict__ p, int n) {
    int i = blockIdx.x * blockDim.x + threadIdx.x;
    if (i < n) p[i] = 0;
}

// bucket histogram: bcnt[dst>>BSHIFT]++
__global__ void k_bhist(const int* __restrict__ dst, int* __restrict__ bcnt,
                        int E, int nbk) {
    __shared__ int c[NBK_MAX];
    int t = threadIdx.x;
    for (int i = t; i < nbk; i += 256) c[i] = 0;
    __syncthreads();
    for (int e = blockIdx.x * blockDim.x + t; e < E; e += gridDim.x * blockDim.x)
        atomicAdd(&c[dst[e] >> BSHIFT], 1);
    __syncthreads();
    for (int i = t; i < nbk; i += 256)
        if (c[i]) atomicAdd(&bcnt[i], c[i]);
}

// single block: exclusive-scan bcnt -> bbase, bcursor; row_ptr[n]=E
__global__ void k_bscan(const int* __restrict__ bcnt, int* __restrict__ bbase,
                        int* __restrict__ bcursor, int* __restrict__ row_ptr,
                        int nbk, int n, int E) {
    __shared__ int s[NBK_MAX];
    int t = threadIdx.x;
    int v0 = (t < nbk) ? bcnt[t] : 0;
    s[t] = v0;
    __syncthreads();
    for (int o = 1; o < 256; o <<= 1) {
        int v = (t >= o) ? s[t - o] : 0;
        __syncthreads();
        s[t] += v;
        __syncthreads();
    }
    int exc = s[t] - v0;
    if (t < nbk) { bbase[t] = exc; bcursor[t] = exc; }
    if (t == 0) { bbase[nbk] = E; row_ptr[n] = E; }
}

// bin (dst,src) pairs into bucket segments of ebuf
__global__ void k_binpairs(const int* __restrict__ src, const int* __restrict__ dst,
                           int* __restrict__ bcursor, int2* __restrict__ ebuf,
                           int E, int nbk) {
    __shared__ int cnt[NBK_MAX], base[NBK_MAX];
    int t = threadIdx.x;
    for (int i = t; i < nbk; i += 256) cnt[i] = 0;
    __syncthreads();
    int e0 = blockIdx.x * (256 * EPT);
    int d[EPT], s[EPT];
#pragma unroll
    for (int j = 0; j < EPT; ++j) {
        int e = e0 + j * 256 + t;
        if (e < E) {
            d[j] = dst[e]; s[j] = src[e];
            atomicAdd(&cnt[d[j] >> BSHIFT], 1);
        } else d[j] = -1;
    }
    __syncthreads();
    for (int i = t; i < nbk; i += 256)
        base[i] = cnt[i] ? atomicAdd(&bcursor[i], cnt[i]) : 0;
    __syncthreads();
    for (int i = t; i < nbk; i += 256) cnt[i] = 0;
    __syncthreads();
#pragma unroll
    for (int j = 0; j < EPT; ++j) {
        if (d[j] >= 0) {
            int b = d[j] >> BSHIFT;
            int r = atomicAdd(&cnt[b], 1);
            ebuf[base[b] + r] = make_int2(d[j], s[j]);
        }
    }
}

// one block per bucket: local count+scan -> row_ptr, dinv, col
__global__ void k_bucket_csr(const int2* __restrict__ ebuf, const int* __restrict__ bbase,
                             int* __restrict__ row_ptr, int* __restrict__ col,
                             float* __restrict__ dinv, int n) {
    __shared__ int cnt[512], ofs[512], cur[512];
    __shared__ int ssum[256];
    int b = blockIdx.x;
    int t = threadIdx.x;
    int nodeBase = b << BSHIFT;
    int nNodes = min(512, n - nodeBase);
    int beg = bbase[b], end = bbase[b + 1];
    cnt[t] = 0; cnt[t + 256] = 0;
    __syncthreads();
    for (int e = beg + t; e < end; e += 256)
        atomicAdd(&cnt[ebuf[e].x - nodeBase], 1);
    __syncthreads();
    int a0 = cnt[2 * t], a1 = cnt[2 * t + 1];
    ssum[t] = a0 + a1;
    __syncthreads();
    for (int o = 1; o < 256; o <<= 1) {
        int v = (t >= o) ? ssum[t - o] : 0;
        __syncthreads();
        ssum[t] += v;
        __syncthreads();
    }
    int exc = ssum[t] - (a0 + a1);
    ofs[2 * t] = exc;       ofs[2 * t + 1] = exc + a0;
    cur[2 * t] = exc;       cur[2 * t + 1] = exc + a0;
    __syncthreads();
    for (int i = t; i < nNodes; i += 256) {
        row_ptr[nodeBase + i] = beg + ofs[i];
        dinv[nodeBase + i] = rsqrtf((float)(cnt[i] + 1));  // +1 self-loop
    }
    __syncthreads();
    for (int e = beg + t; e < end; e += 256) {
        int2 p = ebuf[e];
        int r = atomicAdd(&cur[p.x - nodeBase], 1);
        col[beg + r] = p.y;
    }
}

// out[n,64] = (in @ W) * dinv[row], fp16 output
__global__ void k_gemm64(const float* __restrict__ in, const float* __restrict__ W,
                         const float* __restrict__ dinv, __half* __restrict__ out, int n) {
    __shared__ float Ws[64 * 64];
    int t = threadIdx.x;
#pragma unroll
    for (int j = 0; j < 4; ++j) {
        int idx = (t + j * 256) * 4;
        *(float4*)&Ws[idx] = *(const float4*)&W[idx];
    }
    __syncthreads();
    int row = blockIdx.x * NODES_PER_GEMM_BLOCK + (t >> 4);
    int c = (t & 15) * 4;
    if (row >= n) return;
    const float* inr = in + (size_t)row * 64;
    float4 acc = make_float4(0.f, 0.f, 0.f, 0.f);
#pragma unroll
    for (int k0 = 0; k0 < 64; k0 += 4) {
        float4 xv = *(const float4*)(inr + k0);
        float xs[4] = {xv.x, xv.y, xv.z, xv.w};
#pragma unroll
        for (int j = 0; j < 4; ++j) {
            float4 w = *(const float4*)&Ws[(k0 + j) * 64 + c];
            acc.x += xs[j] * w.x; acc.y += xs[j] * w.y;
            acc.z += xs[j] * w.z; acc.w += xs[j] * w.w;
        }
    }
    float s = dinv[row];
    acc.x *= s; acc.y *= s; acc.z *= s; acc.w *= s;
    st_h4(out, row, c, acc);
}

// gather core: acc = y[node] + sum over col[beg..end); 4-deep unroll
__device__ __forceinline__ float4 gather_row(const __half* __restrict__ y,
                                             const int* __restrict__ col,
                                             int node, int c, int beg, int end) {
    float4 a0 = ld_h4(y, node, c);
    float4 a1 = make_float4(0.f, 0.f, 0.f, 0.f);
    float4 a2 = make_float4(0.f, 0.f, 0.f, 0.f);
    float4 a3 = make_float4(0.f, 0.f, 0.f, 0.f);
    int j = beg;
    for (; j + 3 < end; j += 4) {
        int s0 = col[j], s1 = col[j + 1], s2 = col[j + 2], s3 = col[j + 3];
        float4 v0 = ld_h4(y, s0, c);
        float4 v1 = ld_h4(y, s1, c);
        float4 v2 = ld_h4(y, s2, c);
        float4 v3 = ld_h4(y, s3, c);
        add4(a0, v0); add4(a1, v1); add4(a2, v2); add4(a3, v3);
    }
    for (; j < end; ++j) add4(a1, ld_h4(y, col[j], c));
    add4(a0, a1); add4(a2, a3); add4(a0, a2);
    return a0;
}

// Fused: h = relu((y[d] + sum y[col]) * dinv[d] + b1); y2[d] = (h @ W2)*dinv[d]
__global__ void k_gather_gemm(const __half* __restrict__ y, const int* __restrict__ row_ptr,
                              const int* __restrict__ col, const float* __restrict__ dinv,
                              const float* __restrict__ bias, const float* __restrict__ W,
                              __half* __restrict__ out, int n) {
    __shared__ float Ws[64 * 64];
    __shared__ float rowb[16][68];
    int t = threadIdx.x;
#pragma unroll
    for (int j = 0; j < 4; ++j) {
        int idx = (t + j * 256) * 4;
        *(float4*)&Ws[idx] = *(const float4*)&W[idx];
    }
    int node = blockIdx.x * 16 + (t >> 4);
    int c = (t & 15) * 4;
    int nl = t >> 4;
    bool active = node < n;
    float dn = 0.f;
    if (active) {
        int beg = row_ptr[node], end = row_ptr[node + 1];
        float4 acc = gather_row(y, col, node, c, beg, end);
        dn = dinv[node];
        float4 bb = *(const float4*)&bias[c];
        rowb[nl][c + 0] = fmaxf(acc.x * dn + bb.x, 0.f);
        rowb[nl][c + 1] = fmaxf(acc.y * dn + bb.y, 0.f);
        rowb[nl][c + 2] = fmaxf(acc.z * dn + bb.z, 0.f);
        rowb[nl][c + 3] = fmaxf(acc.w * dn + bb.w, 0.f);
    }
    __syncthreads();
    if (!active) return;
    float4 o = make_float4(0.f, 0.f, 0.f, 0.f);
#pragma unroll
    for (int k0 = 0; k0 < 64; k0 += 4) {
        float4 xv = *(const float4*)&rowb[nl][k0];
        float xs[4] = {xv.x, xv.y, xv.z, xv.w};
#pragma unroll
        for (int j = 0; j < 4; ++j) {
            float4 w = *(const float4*)&Ws[(k0 + j) * 64 + c];
            o.x += xs[j] * w.x; o.y += xs[j] * w.y;
            o.z += xs[j] * w.z; o.w += xs[j] * w.w;
        }
    }
    o.x *= dn; o.y *= dn; o.z *= dn; o.w *= dn;
    st_h4(out, node, c, o);
}

// Fused: h = relu((y[d] + sum y[col]) * dinv[d] + b2); g[batch[d]] += h
__global__ void k_gather_pool(const __half* __restrict__ y, const int* __restrict__ row_ptr,
                              const int* __restrict__ col, const float* __restrict__ dinv,
                              const float* __restrict__ bias, const int* __restrict__ batch,
                              float* __restrict__ g, int n) {
    int t = threadIdx.x;
    int blk0 = (int)blockIdx.x * 16;
    int node = blk0 + (t >> 4);
    int c = (t & 15) * 4;
    __shared__ int bFirst, bLast;
    __shared__ float4 sm[4][16];
    if (t == 0) {
        int i0 = blk0 < n - 1 ? blk0 : n - 1;
        bFirst = batch[i0];
    }
    if (t == 255) {
        int i1 = blk0 + 15 < n - 1 ? blk0 + 15 : n - 1;
        bLast = batch[i1];
    }
    bool active = node < n;
    float4 h = make_float4(0.f, 0.f, 0.f, 0.f);
    int bt = 0;
    if (active) {
        int beg = row_ptr[node], end = row_ptr[node + 1];
        float4 acc = gather_row(y, col, node, c, beg, end);
        float dn = dinv[node];
        float4 bb = *(const float4*)&bias[c];
        h.x = fmaxf(acc.x * dn + bb.x, 0.f);
        h.y = fmaxf(acc.y * dn + bb.y, 0.f);
        h.z = fmaxf(acc.z * dn + bb.z, 0.f);
        h.w = fmaxf(acc.w * dn + bb.w, 0.f);
        bt = batch[node];
    }
    __syncthreads();
    if (bFirst == bLast) {
        float4 v = h;
        v.x += __shfl_xor(v.x, 16, 64); v.y += __shfl_xor(v.y, 16, 64);
        v.z += __shfl_xor(v.z, 16, 64); v.w += __shfl_xor(v.w, 16, 64);
        v.x += __shfl_xor(v.x, 32, 64); v.y += __shfl_xor(v.y, 32, 64);
        v.z += __shfl_xor(v.z, 32, 64); v.w += __shfl_xor(v.w, 32, 64);
        if ((t & 63) < 16) sm[t >> 6][t & 15] = v;
        __syncthreads();
        if (t < 16) {
            float4 a = sm[0][t], b2 = sm[1][t], c2 = sm[2][t], d2 = sm[3][t];
            float4 tot;
            tot.x = a.x + b2.x + c2.x + d2.x; tot.y = a.y + b2.y + c2.y + d2.y;
            tot.z = a.z + b2.z + c2.z + d2.z; tot.w = a.w + b2.w + c2.w + d2.w;
            float* gp = &g[(size_t)bFirst * 64 + t * 4];
            unsafeAtomicAdd(gp + 0, tot.x); unsafeAtomicAdd(gp + 1, tot.y);
            unsafeAtomicAdd(gp + 2, tot.z); unsafeAtomicAdd(gp + 3, tot.w);
        }
    } else if (active) {
        float* gp = &g[(size_t)bt * 64 + c];
        unsafeAtomicAdd(gp + 0, h.x); unsafeAtomicAdd(gp + 1, h.y);
        unsafeAtomicAdd(gp + 2, h.z); unsafeAtomicAdd(gp + 3, h.w);
    }
}

// one block (64 thr) per graph: out = relu(g@fc1+b)@fc2+b
__global__ void k_head(const float* __restrict__ g, const float* __restrict__ fc1w,
                       const float* __restrict__ fc1b, const float* __restrict__ fc2w,
                       const float* __restrict__ fc2b, float* __restrict__ out) {
    int b = blockIdx.x, t = threadIdx.x;
    __shared__ float gl[64];
    gl[t] = g[(size_t)b * 64 + t];
    __syncthreads();
    float acc = fc1b[t];
#pragma unroll 8
    for (int k = 0; k < 64; ++k) acc += gl[k] * fc1w[k * 64 + t];
    float v = fmaxf(acc, 0.f) * fc2w[t];
#pragma unroll
    for (int o = 32; o > 0; o >>= 1) v += __shfl_down(v, o, 64);
    if (t == 0) out[b] = v + fc2b[0];
}

extern "C" void kernel_launch(void* const* d_in, const int* in_sizes, int n_in,
                              void* d_out, int out_size, void* d_ws, size_t ws_size,
                              hipStream_t stream) {
    const float* x    = (const float*)d_in[0];
    const int*   ei   = (const int*)d_in[1];
    const int*   batch= (const int*)d_in[2];
    const float* W1   = (const float*)d_in[3];
    const float* b1   = (const float*)d_in[4];
    const float* W2   = (const float*)d_in[5];
    const float* b2   = (const float*)d_in[6];
    const float* fc1w = (const float*)d_in[7];
    const float* fc1b = (const float*)d_in[8];
    const float* fc2w = (const float*)d_in[9];
    const float* fc2b = (const float*)d_in[10];
    float* out = (float*)d_out;

    int N = in_sizes[0] / 64;   // 100000
    int E = in_sizes[1] / 2;    // 1600000
    const int* src = ei;
    const int* dstp = ei + E;
    int G = out_size;           // 128
    int nbk = (N + (1 << BSHIFT) - 1) >> BSHIFT;  // 196

    // workspace layout (4-byte word units). N*32 words == E*2 words == 12.8MB.
    float*  base    = (float*)d_ws;
    __half* y1      = (__half*)base;                     // [N*64] halves = N*32 words
    float*  scratch = base + (size_t)N * 32;             // max(ebuf E*2, y2 N*32)
    int2*   ebuf    = (int2*)scratch;                    // [E] pairs
    __half* y2      = (__half*)scratch;                  // [N*64] halves (after ebuf dead)
    size_t  scr_w   = (size_t)(N * 32 > E * 2 ? N * 32 : E * 2);
    float*  dinv    = scratch + scr_w;                   // [N]
    int*    row_ptr = (int*)(dinv + N);                  // [N+1]
    int*    col     = row_ptr + (N + 1);                 // [E]
    int*    bbase   = col + E;                           // [NBK_MAX+1]
    int*    bcursor = bbase + (NBK_MAX + 1);             // [NBK_MAX]
    int*    bcnt    = bcursor + NBK_MAX;                 // [NBK_MAX]
    float*  g       = (float*)(bcnt + NBK_MAX);          // [G*64] (needs zero)

    dim3 blk(256);
    int nzero = NBK_MAX + G * 64;          // bcnt + g contiguous
    int nb_pairs = (E + 256 * EPT - 1) / (256 * EPT);
    int nb_gemm  = (N + NODES_PER_GEMM_BLOCK - 1) / NODES_PER_GEMM_BLOCK;
    int nb_g16   = (N + 15) / 16;

    // CSR build (bucketed counting sort)
    k_zero_int<<<(nzero + 255) / 256, blk, 0, stream>>>(bcnt, nzero);
    k_bhist<<<1024, blk, 0, stream>>>(dstp, bcnt, E, nbk);
    k_bscan<<<1, blk, 0, stream>>>(bcnt, bbase, bcursor, row_ptr, nbk, N, E);
    k_binpairs<<<nb_pairs, blk, 0, stream>>>(src, dstp, bcursor, ebuf, E, nbk);
    k_bucket_csr<<<nbk, blk, 0, stream>>>(ebuf, bbase, row_ptr, col, dinv, N);

    // layer 1 gemm: y1 = (x @ W1)*dinv   (fp16 out)
    k_gemm64<<<nb_gemm, blk, 0, stream>>>(x, W1, dinv, y1, N);
    // fused layer1-aggregate + layer2 gemm: y2 = (relu(agg(y1)+b1) @ W2)*dinv
    k_gather_gemm<<<nb_g16, blk, 0, stream>>>(y1, row_ptr, col, dinv, b1, W2, y2, N);
    // fused layer2-aggregate + relu + pool: g += relu(agg(y2)+b2)
    k_gather_pool<<<nb_g16, blk, 0, stream>>>(y2, row_ptr, col, dinv, b2, batch, g, N);
    // MLP head
    k_head<<<G, 64, 0, stream>>>(g, fc1w, fc1b, fc2w, fc2b, out);
}

// Round 6
// 208.679 us; speedup vs baseline: 14.0247x; 1.0713x over previous
//
#include <hip/hip_runtime.h>
#include <hip/hip_fp16.h>

// Net_66829691126193: 2-layer GCN + global_add_pool + 2-layer MLP head.
// N=100000 nodes, E=1600000 edges, F=H=64, G=128 graphs.
// CSR by bucketed counting sort; gather aggregation with fp16 rows,
// 8 lanes/node x 16B loads, 8-deep masked unroll for MLP.

#define NODES_PER_GEMM_BLOCK 16
#define BSHIFT 9
#define NBK_MAX 256
#define EPT 16

union HU2 { uint2 u; __half2 h[2]; };
union HU4 { uint4 u; __half2 h[4]; };

__device__ __forceinline__ void st_h4(__half* __restrict__ y, int node, int c, float4 v) {
    HU2 p;
    p.h[0] = __floats2half2_rn(v.x, v.y);
    p.h[1] = __floats2half2_rn(v.z, v.w);
    *(uint2*)(y + ((size_t)node << 6) + c) = p.u;
}

__device__ __forceinline__ void accum8(float* a, const HU4& p, float m) {
#pragma unroll
    for (int q = 0; q < 4; ++q) {
        float2 f = __half22float2(p.h[q]);
        a[2 * q]     = fmaf(f.x, m, a[2 * q]);
        a[2 * q + 1] = fmaf(f.y, m, a[2 * q + 1]);
    }
}

// acc[8] += y[node][c8..c8+7] + sum_{j in [beg,end)} y[col[j]][c8..c8+7]
__device__ __forceinline__ void gather_row8(float* acc, const __half* __restrict__ y,
                                            const int* __restrict__ col,
                                            int node, int c8, int beg, int end) {
    HU4 self;
    self.u = *(const uint4*)(y + ((size_t)node << 6) + c8);
    accum8(acc, self, 1.0f);
    int lim = end - 1;
    for (int j = beg; j < end; j += 8) {
        HU4 v[8];
#pragma unroll
        for (int u = 0; u < 8; ++u) {
            int p = (j + u <= lim) ? j + u : lim;
            v[u].u = *(const uint4*)(y + ((size_t)col[p] << 6) + c8);
        }
#pragma unroll
        for (int u = 0; u < 8; ++u)
            accum8(acc, v[u], (j + u <= lim) ? 1.0f : 0.0f);
    }
}

__global__ void k_zero_int(int* __restrict__ p, int n) {
    int i = blockIdx.x * blockDim.x + threadIdx.x;
    if (i < n) p[i] = 0;
}

// bucket histogram: bcnt[dst>>BSHIFT]++
__global__ void k_bhist(const int* __restrict__ dst, int* __restrict__ bcnt,
                        int E, int nbk) {
    __shared__ int c[NBK_MAX];
    int t = threadIdx.x;
    for (int i = t; i < nbk; i += 256) c[i] = 0;
    __syncthreads();
    for (int e = blockIdx.x * blockDim.x + t; e < E; e += gridDim.x * blockDim.x)
        atomicAdd(&c[dst[e] >> BSHIFT], 1);
    __syncthreads();
    for (int i = t; i < nbk; i += 256)
        if (c[i]) atomicAdd(&bcnt[i], c[i]);
}

// single block: exclusive-scan bcnt -> bbase, bcursor; row_ptr[n]=E
__global__ void k_bscan(const int* __restrict__ bcnt, int* __restrict__ bbase,
                        int* __restrict__ bcursor, int* __restrict__ row_ptr,
                        int nbk, int n, int E) {
    __shared__ int s[NBK_MAX];
    int t = threadIdx.x;
    int v0 = (t < nbk) ? bcnt[t] : 0;
    s[t] = v0;
    __syncthreads();
    for (int o = 1; o < 256; o <<= 1) {
        int v = (t >= o) ? s[t - o] : 0;
        __syncthreads();
        s[t] += v;
        __syncthreads();
    }
    int exc = s[t] - v0;
    if (t < nbk) { bbase[t] = exc; bcursor[t] = exc; }
    if (t == 0) { bbase[nbk] = E; row_ptr[n] = E; }
}

// bin (dst,src) pairs into bucket segments of ebuf
__global__ void k_binpairs(const int* __restrict__ src, const int* __restrict__ dst,
                           int* __restrict__ bcursor, int2* __restrict__ ebuf,
                           int E, int nbk) {
    __shared__ int cnt[NBK_MAX], base[NBK_MAX];
    int t = threadIdx.x;
    for (int i = t; i < nbk; i += 256) cnt[i] = 0;
    __syncthreads();
    int e0 = blockIdx.x * (256 * EPT);
    int d[EPT], s[EPT];
#pragma unroll
    for (int j = 0; j < EPT; ++j) {
        int e = e0 + j * 256 + t;
        if (e < E) {
            d[j] = dst[e]; s[j] = src[e];
            atomicAdd(&cnt[d[j] >> BSHIFT], 1);
        } else d[j] = -1;
    }
    __syncthreads();
    for (int i = t; i < nbk; i += 256)
        base[i] = cnt[i] ? atomicAdd(&bcursor[i], cnt[i]) : 0;
    __syncthreads();
    for (int i = t; i < nbk; i += 256) cnt[i] = 0;
    __syncthreads();
#pragma unroll
    for (int j = 0; j < EPT; ++j) {
        if (d[j] >= 0) {
            int b = d[j] >> BSHIFT;
            int r = atomicAdd(&cnt[b], 1);
            ebuf[base[b] + r] = make_int2(d[j], s[j]);
        }
    }
}

// one block per bucket: local count+scan -> row_ptr, dinv, col
__global__ void k_bucket_csr(const int2* __restrict__ ebuf, const int* __restrict__ bbase,
                             int* __restrict__ row_ptr, int* __restrict__ col,
                             float* __restrict__ dinv, int n) {
    __shared__ int cnt[512], ofs[512], cur[512];
    __shared__ int ssum[256];
    int b = blockIdx.x;
    int t = threadIdx.x;
    int nodeBase = b << BSHIFT;
    int nNodes = min(512, n - nodeBase);
    int beg = bbase[b], end = bbase[b + 1];
    cnt[t] = 0; cnt[t + 256] = 0;
    __syncthreads();
    for (int e = beg + t; e < end; e += 256)
        atomicAdd(&cnt[ebuf[e].x - nodeBase], 1);
    __syncthreads();
    int a0 = cnt[2 * t], a1 = cnt[2 * t + 1];
    ssum[t] = a0 + a1;
    __syncthreads();
    for (int o = 1; o < 256; o <<= 1) {
        int v = (t >= o) ? ssum[t - o] : 0;
        __syncthreads();
        ssum[t] += v;
        __syncthreads();
    }
    int exc = ssum[t] - (a0 + a1);
    ofs[2 * t] = exc;       ofs[2 * t + 1] = exc + a0;
    cur[2 * t] = exc;       cur[2 * t + 1] = exc + a0;
    __syncthreads();
    for (int i = t; i < nNodes; i += 256) {
        row_ptr[nodeBase + i] = beg + ofs[i];
        dinv[nodeBase + i] = rsqrtf((float)(cnt[i] + 1));  // +1 self-loop
    }
    __syncthreads();
    for (int e = beg + t; e < end; e += 256) {
        int2 p = ebuf[e];
        int r = atomicAdd(&cur[p.x - nodeBase], 1);
        col[beg + r] = p.y;
    }
}

// out[n,64] = (in @ W) * dinv[row], fp16 output
__global__ void k_gemm64(const float* __restrict__ in, const float* __restrict__ W,
                         const float* __restrict__ dinv, __half* __restrict__ out, int n) {
    __shared__ float Ws[64 * 64];
    int t = threadIdx.x;
#pragma unroll
    for (int j = 0; j < 4; ++j) {
        int idx = (t + j * 256) * 4;
        *(float4*)&Ws[idx] = *(const float4*)&W[idx];
    }
    __syncthreads();
    int row = blockIdx.x * NODES_PER_GEMM_BLOCK + (t >> 4);
    int c = (t & 15) * 4;
    if (row >= n) return;
    const float* inr = in + (size_t)row * 64;
    float4 acc = make_float4(0.f, 0.f, 0.f, 0.f);
#pragma unroll
    for (int k0 = 0; k0 < 64; k0 += 4) {
        float4 xv = *(const float4*)(inr + k0);
        float xs[4] = {xv.x, xv.y, xv.z, xv.w};
#pragma unroll
        for (int j = 0; j < 4; ++j) {
            float4 w = *(const float4*)&Ws[(k0 + j) * 64 + c];
            acc.x += xs[j] * w.x; acc.y += xs[j] * w.y;
            acc.z += xs[j] * w.z; acc.w += xs[j] * w.w;
        }
    }
    float s = dinv[row];
    acc.x *= s; acc.y *= s; acc.z *= s; acc.w *= s;
    st_h4(out, row, c, acc);
}

// Fused: h = relu((y[d] + sum y[col]) * dinv[d] + b1); y2[d] = (h @ W2)*dinv[d]
// 8 lanes/node, 32 nodes/block.
__global__ void k_gather_gemm(const __half* __restrict__ y, const int* __restrict__ row_ptr,
                              const int* __restrict__ col, const float* __restrict__ dinv,
                              const float* __restrict__ bias, const float* __restrict__ W,
                              __half* __restrict__ out, int n) {
    __shared__ float Ws[64 * 64];
    __shared__ float rowb[32][72];
    int t = threadIdx.x;
#pragma unroll
    for (int j = 0; j < 4; ++j) {
        int idx = (t + j * 256) * 4;
        *(float4*)&Ws[idx] = *(const float4*)&W[idx];
    }
    int nl = t >> 3;
    int node = blockIdx.x * 32 + nl;
    int c8 = (t & 7) * 8;
    bool active = node < n;
    float dn = 0.f;
    if (active) {
        float acc[8] = {0.f, 0.f, 0.f, 0.f, 0.f, 0.f, 0.f, 0.f};
        int beg = row_ptr[node], end = row_ptr[node + 1];
        gather_row8(acc, y, col, node, c8, beg, end);
        dn = dinv[node];
#pragma unroll
        for (int f = 0; f < 8; ++f)
            rowb[nl][c8 + f] = fmaxf(fmaf(acc[f], dn, bias[c8 + f]), 0.f);
    }
    __syncthreads();
    if (!active) return;
    float o[8] = {0.f, 0.f, 0.f, 0.f, 0.f, 0.f, 0.f, 0.f};
#pragma unroll 8
    for (int k = 0; k < 64; ++k) {
        float xk = rowb[nl][k];
        const float* wr = &Ws[k * 64 + c8];
#pragma unroll
        for (int f = 0; f < 8; ++f) o[f] = fmaf(xk, wr[f], o[f]);
    }
    HU4 p;
#pragma unroll
    for (int q = 0; q < 4; ++q)
        p.h[q] = __floats2half2_rn(o[2 * q] * dn, o[2 * q + 1] * dn);
    *(uint4*)(out + ((size_t)node << 6) + c8) = p.u;
}

// Fused: h = relu((y[d] + sum y[col]) * dinv[d] + b2); g[batch[d]] += h
// 8 lanes/node, 32 nodes/block.
__global__ void k_gather_pool(const __half* __restrict__ y, const int* __restrict__ row_ptr,
                              const int* __restrict__ col, const float* __restrict__ dinv,
                              const float* __restrict__ bias, const int* __restrict__ batch,
                              float* __restrict__ g, int n) {
    int t = threadIdx.x;
    int blk0 = (int)blockIdx.x * 32;
    int nl = t >> 3;
    int node = blk0 + nl;
    int c8 = (t & 7) * 8;
    __shared__ int bFirst, bLast;
    __shared__ float gl[4 * 64];
    if (t == 0) {
        int i0 = blk0 < n - 1 ? blk0 : n - 1;
        bFirst = batch[i0];
    }
    if (t == 255) {
        int i1 = blk0 + 31 < n - 1 ? blk0 + 31 : n - 1;
        bLast = batch[i1];
    }
    bool active = node < n;
    float h[8] = {0.f, 0.f, 0.f, 0.f, 0.f, 0.f, 0.f, 0.f};
    int bt = 0;
    if (active) {
        float acc[8] = {0.f, 0.f, 0.f, 0.f, 0.f, 0.f, 0.f, 0.f};
        int beg = row_ptr[node], end = row_ptr[node + 1];
        gather_row8(acc, y, col, node, c8, beg, end);
        float dn = dinv[node];
#pragma unroll
        for (int f = 0; f < 8; ++f)
            h[f] = fmaxf(fmaf(acc[f], dn, bias[c8 + f]), 0.f);
        bt = batch[node];
    }
    __syncthreads();
    if (bFirst == bLast) {
        // all nodes in block belong to graph bFirst: tree-reduce then 64 atomics
#pragma unroll
        for (int f = 0; f < 8; ++f) {
            h[f] += __shfl_xor(h[f], 8, 64);
            h[f] += __shfl_xor(h[f], 16, 64);
            h[f] += __shfl_xor(h[f], 32, 64);
        }
        int wv = t >> 6;
        if ((t & 63) < 8) {
#pragma unroll
            for (int f = 0; f < 8; ++f) gl[wv * 64 + (t & 7) * 8 + f] = h[f];
        }
        __syncthreads();
        if (t < 64) {
            float tot = gl[t] + gl[64 + t] + gl[128 + t] + gl[192 + t];
            unsafeAtomicAdd(&g[(size_t)bFirst * 64 + t], tot);
        }
    } else if (active) {
        float* gp = &g[(size_t)bt * 64 + c8];
#pragma unroll
        for (int f = 0; f < 8; ++f) unsafeAtomicAdd(gp + f, h[f]);
    }
}

// one block (64 thr) per graph: out = relu(g@fc1+b)@fc2+b
__global__ void k_head(const float* __restrict__ g, const float* __restrict__ fc1w,
                       const float* __restrict__ fc1b, const float* __restrict__ fc2w,
                       const float* __restrict__ fc2b, float* __restrict__ out) {
    int b = blockIdx.x, t = threadIdx.x;
    __shared__ float gl[64];
    gl[t] = g[(size_t)b * 64 + t];
    __syncthreads();
    float acc = fc1b[t];
#pragma unroll 8
    for (int k = 0; k < 64; ++k) acc += gl[k] * fc1w[k * 64 + t];
    float v = fmaxf(acc, 0.f) * fc2w[t];
#pragma unroll
    for (int o = 32; o > 0; o >>= 1) v += __shfl_down(v, o, 64);
    if (t == 0) out[b] = v + fc2b[0];
}

extern "C" void kernel_launch(void* const* d_in, const int* in_sizes, int n_in,
                              void* d_out, int out_size, void* d_ws, size_t ws_size,
                              hipStream_t stream) {
    const float* x    = (const float*)d_in[0];
    const int*   ei   = (const int*)d_in[1];
    const int*   batch= (const int*)d_in[2];
    const float* W1   = (const float*)d_in[3];
    const float* b1   = (const float*)d_in[4];
    const float* W2   = (const float*)d_in[5];
    const float* b2   = (const float*)d_in[6];
    const float* fc1w = (const float*)d_in[7];
    const float* fc1b = (const float*)d_in[8];
    const float* fc2w = (const float*)d_in[9];
    const float* fc2b = (const float*)d_in[10];
    float* out = (float*)d_out;

    int N = in_sizes[0] / 64;   // 100000
    int E = in_sizes[1] / 2;    // 1600000
    const int* src = ei;
    const int* dstp = ei + E;
    int G = out_size;           // 128
    int nbk = (N + (1 << BSHIFT) - 1) >> BSHIFT;  // 196

    // workspace layout (4-byte word units). N*32 words == E*2 words == 12.8MB.
    float*  base    = (float*)d_ws;
    __half* y1      = (__half*)base;                     // [N*64] halves = N*32 words
    float*  scratch = base + (size_t)N * 32;             // max(ebuf E*2, y2 N*32)
    int2*   ebuf    = (int2*)scratch;                    // [E] pairs
    __half* y2      = (__half*)scratch;                  // [N*64] halves (after ebuf dead)
    size_t  scr_w   = (size_t)(N * 32 > E * 2 ? N * 32 : E * 2);
    float*  dinv    = scratch + scr_w;                   // [N]
    int*    row_ptr = (int*)(dinv + N);                  // [N+1]
    int*    col     = row_ptr + (N + 1);                 // [E]
    int*    bbase   = col + E;                           // [NBK_MAX+1]
    int*    bcursor = bbase + (NBK_MAX + 1);             // [NBK_MAX]
    int*    bcnt    = bcursor + NBK_MAX;                 // [NBK_MAX]
    float*  g       = (float*)(bcnt + NBK_MAX);          // [G*64] (needs zero)

    dim3 blk(256);
    int nzero = NBK_MAX + G * 64;          // bcnt + g contiguous
    int nb_pairs = (E + 256 * EPT - 1) / (256 * EPT);
    int nb_gemm  = (N + NODES_PER_GEMM_BLOCK - 1) / NODES_PER_GEMM_BLOCK;
    int nb_g32   = (N + 31) / 32;

    // CSR build (bucketed counting sort)
    k_zero_int<<<(nzero + 255) / 256, blk, 0, stream>>>(bcnt, nzero);
    k_bhist<<<1024, blk, 0, stream>>>(dstp, bcnt, E, nbk);
    k_bscan<<<1, blk, 0, stream>>>(bcnt, bbase, bcursor, row_ptr, nbk, N, E);
    k_binpairs<<<nb_pairs, blk, 0, stream>>>(src, dstp, bcursor, ebuf, E, nbk);
    k_bucket_csr<<<nbk, blk, 0, stream>>>(ebuf, bbase, row_ptr, col, dinv, N);

    // layer 1 gemm: y1 = (x @ W1)*dinv   (fp16 out)
    k_gemm64<<<nb_gemm, blk, 0, stream>>>(x, W1, dinv, y1, N);
    // fused layer1-aggregate + layer2 gemm: y2 = (relu(agg(y1)+b1) @ W2)*dinv
    k_gather_gemm<<<nb_g32, blk, 0, stream>>>(y1, row_ptr, col, dinv, b1, W2, y2, N);
    // fused layer2-aggregate + relu + pool: g += relu(agg(y2)+b2)
    k_gather_pool<<<nb_g32, blk, 0, stream>>>(y2, row_ptr, col, dinv, b2, batch, g, N);
    // MLP head
    k_head<<<G, 64, 0, stream>>>(g, fc1w, fc1b, fc2w, fc2b, out);
}